// Round 5
// baseline (344.086 us; speedup 1.0000x reference)
//
#include <hip/hip_runtime.h>
#include <hip/hip_fp16.h>

// HierarchicalStaticNeuralTexture — round 5: UV-bucketed gather for L2 locality.
//
//   uv_inputs: [1, 2, 1024, 1024] f32, coords in [-1,1]
//   data:      [1, 16, 2048, 1024] f32  (4 mip levels stacked in Y)
//   out:       [1, 16, 1024, 1024] f32 = sum over 4 levels of bilinear
//              grid_sample (border padding, align_corners=False)
//
// Pipeline:
//   1. transpose_h : atlas -> fp16 texel-major (32 B / texel)
//   2. zero+hist+scan+scatter : counting-sort pixels by 32x32 UV tile
//   3. sample_b    : sorted-order sampling (bucket-local L2 reuse),
//                    fp16 result to tmp (coalesced)
//   4. unperm      : gather tmp by inverse rank, write channel planes

#define IMG 1024
#define NPIX (IMG * IMG)
#define NCH 16
#define DATA_ROWSTRIDE 1024
#define DATA_CHSTRIDE (2048 * 1024)
#define NBUCK 1024

// Compact texel-major layout (texel index -> 16 halves)
#define L0_BASE 0
#define L1_BASE 1048576          // 1024*1024
#define L2_BASE 1310720          // + 512*512
#define L3_BASE 1376256          // + 256*256
#define TOT_TEXELS 1392640       // + 128*128

// Workspace layout (bytes, all 256-aligned)
#define TEX_BYTES  44564480ull                    // TOT_TEXELS*16*2
#define UVS_OFF    44564480ull                    // float2 * NPIX = 8388608
#define INV_OFF    52953088ull                    // u32 * NPIX   = 4194304
#define TMP_OFF    57147392ull                    // half*16*NPIX = 33554432
#define CNT_OFF    90701824ull                    // hist[1024] + cursor[1024]
#define WS_FULL    (CNT_OFF + 8192ull)            // 90,710,016
#define WS_DIRECT  TEX_BYTES                      // fallback path

// ---------------- transpose+quantize: data[c][y][x] -> tex16[(base+t)*16+c] --
__global__ __launch_bounds__(256) void hsnt_transpose_h(
    const float* __restrict__ data, __half* __restrict__ tex)
{
    int b = blockIdx.x;
    int base, offY, logW;
    if (b < 4096)      { base = L0_BASE; offY = 0;    logW = 10; }
    else if (b < 5120) { base = L1_BASE; offY = 1024; logW = 9;  b -= 4096; }
    else if (b < 5376) { base = L2_BASE; offY = 1536; logW = 8;  b -= 5120; }
    else               { base = L3_BASE; offY = 1792; logW = 7;  b -= 5376; }

    const int t = b * 256 + threadIdx.x;
    const int y = t >> logW;
    const int x = t & ((1 << logW) - 1);

    const float* src = data + (size_t)(offY + y) * DATA_ROWSTRIDE + x;
    __half h[NCH];
#pragma unroll
    for (int c = 0; c < NCH; ++c)
        h[c] = __float2half(src[(size_t)c * DATA_CHSTRIDE]);

    uint4* dst = (uint4*)(tex + ((size_t)(base + t) << 4));
    dst[0] = *(const uint4*)&h[0];
    dst[1] = *(const uint4*)&h[8];
}

// ---------------- bucket key: 32x32 tiles of the L0 texel grid ---------------
__device__ __forceinline__ int bucket_of(const float gx, const float gy)
{
    const float x = fminf(fmaxf(fmaf(gx + 1.0f, 512.0f, -0.5f), 0.0f), 1023.0f);
    const float y = fminf(fmaxf(fmaf(gy + 1.0f, 512.0f, -0.5f), 0.0f), 1023.0f);
    return (((int)y) >> 5) * 32 + (((int)x) >> 5);
}

__global__ __launch_bounds__(256) void hsnt_zero(unsigned* __restrict__ p)
{
    p[blockIdx.x * 256 + threadIdx.x] = 0u;
}

__global__ __launch_bounds__(256) void hsnt_hist(
    const float* __restrict__ uv, unsigned* __restrict__ hist)
{
    __shared__ unsigned lh[NBUCK];
    for (int i = threadIdx.x; i < NBUCK; i += 256) lh[i] = 0u;
    __syncthreads();

    const int base = blockIdx.x * 1024;
#pragma unroll
    for (int k = 0; k < 4; ++k) {
        const int idx = base + k * 256 + threadIdx.x;
        atomicAdd(&lh[bucket_of(uv[idx], uv[NPIX + idx])], 1u);
    }
    __syncthreads();
    for (int i = threadIdx.x; i < NBUCK; i += 256)
        if (lh[i]) atomicAdd(&hist[i], lh[i]);
}

__global__ __launch_bounds__(1024) void hsnt_scan(
    const unsigned* __restrict__ hist, unsigned* __restrict__ cursor)
{
    __shared__ unsigned s[NBUCK];
    const int t = threadIdx.x;
    const unsigned v = hist[t];
    s[t] = v;
    __syncthreads();
    unsigned acc = v;
    for (int off = 1; off < NBUCK; off <<= 1) {
        const unsigned add = (t >= off) ? s[t - off] : 0u;
        __syncthreads();
        acc += add;
        s[t] = acc;
        __syncthreads();
    }
    cursor[t] = acc - v;   // exclusive prefix
}

__global__ __launch_bounds__(256) void hsnt_scatter(
    const float* __restrict__ uv, unsigned* __restrict__ cursor,
    float2* __restrict__ uvs, unsigned* __restrict__ inv)
{
    const int idx = blockIdx.x * 256 + threadIdx.x;
    const float gx = uv[idx];
    const float gy = uv[NPIX + idx];
    const unsigned pos = atomicAdd(&cursor[bucket_of(gx, gy)], 1u);
    uvs[pos] = make_float2(gx, gy);
    inv[idx] = pos;
}

// ---------------- bucketed sampling ------------------------------------------
__device__ __forceinline__ void accum_texel(
    float* __restrict__ acc, const __half* __restrict__ tp, const float w)
{
    union U { uint4 u; __half2 h[4]; } a, b;
    a.u = *(const uint4*)tp;
    b.u = *(const uint4*)(tp + 8);
#pragma unroll
    for (int i = 0; i < 4; ++i) {
        const float2 f = __half22float2(a.h[i]);
        acc[2 * i]     = fmaf(f.x, w, acc[2 * i]);
        acc[2 * i + 1] = fmaf(f.y, w, acc[2 * i + 1]);
        const float2 g = __half22float2(b.h[i]);
        acc[8 + 2 * i]     = fmaf(g.x, w, acc[8 + 2 * i]);
        acc[8 + 2 * i + 1] = fmaf(g.y, w, acc[8 + 2 * i + 1]);
    }
}

__global__ __launch_bounds__(256) void hsnt_sample_b(
    const float2* __restrict__ uvs,
    const __half* __restrict__ tex,
    __half* __restrict__ tmp)
{
    // XCD-chunked swizzle: each XCD gets a contiguous range of sorted order
    const int bid = blockIdx.x;
    const int swz = (bid & 7) * (4096 / 8) + (bid >> 3);
    const int s = swz * 256 + threadIdx.x;

    const float2 g = uvs[s];
    const float gx = g.x;
    const float gy = g.y;

    float acc[NCH];
#pragma unroll
    for (int c = 0; c < NCH; ++c) acc[c] = 0.0f;

    const int BASE[4] = { L0_BASE, L1_BASE, L2_BASE, L3_BASE };

#pragma unroll
    for (int l = 0; l < 4; ++l) {
        const int   W  = 1024 >> l;
        const float Wf = (float)W;

        float x = fminf(fmaxf(fmaf(gx + 1.0f, Wf * 0.5f, -0.5f), 0.0f), Wf - 1.0f);
        float y = fminf(fmaxf(fmaf(gy + 1.0f, Wf * 0.5f, -0.5f), 0.0f), Wf - 1.0f);

        const float x0f = floorf(x);
        const float y0f = floorf(y);
        const float wx = x - x0f;
        const float wy = y - y0f;
        const int x0 = (int)x0f;
        const int y0 = (int)y0f;
        const int x1 = min(x0 + 1, W - 1);
        const int y1 = min(y0 + 1, W - 1);

        const float w11 = wx * wy;
        const float w10 = wy - w11;
        const float w01 = wx - w11;
        const float w00 = 1.0f - wx - wy + w11;

        const int r0 = BASE[l] + y0 * W;
        const int r1 = BASE[l] + y1 * W;

        accum_texel(acc, tex + ((size_t)(r0 + x0) << 4), w00);
        accum_texel(acc, tex + ((size_t)(r0 + x1) << 4), w01);
        accum_texel(acc, tex + ((size_t)(r1 + x0) << 4), w10);
        accum_texel(acc, tex + ((size_t)(r1 + x1) << 4), w11);
    }

    __half h[NCH];
#pragma unroll
    for (int c = 0; c < NCH; ++c) h[c] = __float2half(acc[c]);

    uint4* dst = (uint4*)(tmp + ((size_t)s << 4));
    dst[0] = *(const uint4*)&h[0];
    dst[1] = *(const uint4*)&h[8];
}

// ---------------- unpermute: tmp[rank] -> out channel planes -----------------
__global__ __launch_bounds__(256) void hsnt_unperm(
    const unsigned* __restrict__ inv,
    const __half* __restrict__ tmp,
    float* __restrict__ out)
{
    const int idx = blockIdx.x * 256 + threadIdx.x;
    const unsigned r = inv[idx];

    const uint4* p = (const uint4*)(tmp + ((size_t)r << 4));
    union U { uint4 u; __half2 h[4]; } a, b;
    a.u = p[0];
    b.u = p[1];

#pragma unroll
    for (int i = 0; i < 4; ++i) {
        const float2 f = __half22float2(a.h[i]);
        out[(size_t)(2 * i)     * NPIX + idx] = f.x;
        out[(size_t)(2 * i + 1) * NPIX + idx] = f.y;
        const float2 q = __half22float2(b.h[i]);
        out[(size_t)(8 + 2 * i)     * NPIX + idx] = q.x;
        out[(size_t)(8 + 2 * i + 1) * NPIX + idx] = q.y;
    }
}

// ---------------- direct fp16 path (fallback if ws < WS_FULL) ----------------
__global__ __launch_bounds__(256) void hsnt_sample_h(
    const float* __restrict__ uv,
    const __half* __restrict__ tex,
    float* __restrict__ out)
{
    const int idx = blockIdx.x * blockDim.x + threadIdx.x;
    if (idx >= NPIX) return;

    const float gx = uv[idx];
    const float gy = uv[NPIX + idx];

    float acc[NCH];
#pragma unroll
    for (int c = 0; c < NCH; ++c) acc[c] = 0.0f;

    const int BASE[4] = { L0_BASE, L1_BASE, L2_BASE, L3_BASE };

#pragma unroll
    for (int l = 0; l < 4; ++l) {
        const int   W  = 1024 >> l;
        const float Wf = (float)W;
        float x = fminf(fmaxf(fmaf(gx + 1.0f, Wf * 0.5f, -0.5f), 0.0f), Wf - 1.0f);
        float y = fminf(fmaxf(fmaf(gy + 1.0f, Wf * 0.5f, -0.5f), 0.0f), Wf - 1.0f);
        const float x0f = floorf(x);
        const float y0f = floorf(y);
        const float wx = x - x0f;
        const float wy = y - y0f;
        const int x0 = (int)x0f;
        const int y0 = (int)y0f;
        const int x1 = min(x0 + 1, W - 1);
        const int y1 = min(y0 + 1, W - 1);
        const float w11 = wx * wy;
        const float w10 = wy - w11;
        const float w01 = wx - w11;
        const float w00 = 1.0f - wx - wy + w11;
        const int r0 = BASE[l] + y0 * W;
        const int r1 = BASE[l] + y1 * W;
        accum_texel(acc, tex + ((size_t)(r0 + x0) << 4), w00);
        accum_texel(acc, tex + ((size_t)(r0 + x1) << 4), w01);
        accum_texel(acc, tex + ((size_t)(r1 + x0) << 4), w10);
        accum_texel(acc, tex + ((size_t)(r1 + x1) << 4), w11);
    }

#pragma unroll
    for (int c = 0; c < NCH; ++c)
        out[(size_t)c * NPIX + idx] = acc[c];
}

// ---------------- naive fallback ---------------------------------------------
__global__ __launch_bounds__(256) void hsnt_naive(
    const float* __restrict__ uv,
    const float* __restrict__ data,
    float* __restrict__ out)
{
    const int idx = blockIdx.x * blockDim.x + threadIdx.x;
    if (idx >= NPIX) return;

    const float gx = uv[idx];
    const float gy = uv[NPIX + idx];

    float acc[NCH];
#pragma unroll
    for (int c = 0; c < NCH; ++c) acc[c] = 0.0f;

    int offY = 0;
    int W = 1024;
#pragma unroll
    for (int l = 0; l < 4; ++l) {
        const float Wf = (float)W;
        float x = fminf(fmaxf(fmaf(gx + 1.0f, Wf * 0.5f, -0.5f), 0.0f), Wf - 1.0f);
        float y = fminf(fmaxf(fmaf(gy + 1.0f, Wf * 0.5f, -0.5f), 0.0f), Wf - 1.0f);
        const float x0f = floorf(x);
        const float y0f = floorf(y);
        const float wx = x - x0f;
        const float wy = y - y0f;
        const int x0 = (int)x0f;
        const int y0 = (int)y0f;
        const int x1 = min(x0 + 1, W - 1);
        const int y1 = min(y0 + 1, W - 1);
        const float w11 = wx * wy;
        const float w10 = wy - w11;
        const float w01 = wx - w11;
        const float w00 = 1.0f - wx - wy + w11;
        const int r0 = offY + y0;
        const int r1 = offY + y1;
        const float* p00 = data + (size_t)r0 * DATA_ROWSTRIDE + x0;
        const float* p01 = data + (size_t)r0 * DATA_ROWSTRIDE + x1;
        const float* p10 = data + (size_t)r1 * DATA_ROWSTRIDE + x0;
        const float* p11 = data + (size_t)r1 * DATA_ROWSTRIDE + x1;
#pragma unroll
        for (int c = 0; c < NCH; ++c) {
            const size_t co = (size_t)c * DATA_CHSTRIDE;
            acc[c] = fmaf(p00[co], w00,
                     fmaf(p01[co], w01,
                     fmaf(p10[co], w10,
                     fmaf(p11[co], w11, acc[c]))));
        }
        offY += W;
        W >>= 1;
    }
#pragma unroll
    for (int c = 0; c < NCH; ++c)
        out[(size_t)c * NPIX + idx] = acc[c];
}

extern "C" void kernel_launch(void* const* d_in, const int* in_sizes, int n_in,
                              void* d_out, int out_size, void* d_ws, size_t ws_size,
                              hipStream_t stream) {
    const float* uv   = (const float*)d_in[0];   // [1,2,1024,1024]
    const float* data = (const float*)d_in[1];   // [1,16,2048,1024]
    float* out = (float*)d_out;                  // [1,16,1024,1024]

    const int grid = NPIX / 256;                 // 4096

    if (ws_size >= WS_FULL && d_ws != nullptr) {
        char* ws = (char*)d_ws;
        __half*   tex    = (__half*)ws;
        float2*   uvs    = (float2*)(ws + UVS_OFF);
        unsigned* inv    = (unsigned*)(ws + INV_OFF);
        __half*   tmp    = (__half*)(ws + TMP_OFF);
        unsigned* hist   = (unsigned*)(ws + CNT_OFF);
        unsigned* cursor = hist + NBUCK;

        hsnt_transpose_h<<<TOT_TEXELS / 256, 256, 0, stream>>>(data, tex);
        hsnt_zero<<<NBUCK / 256, 256, 0, stream>>>(hist);
        hsnt_hist<<<NPIX / 1024, 256, 0, stream>>>(uv, hist);
        hsnt_scan<<<1, NBUCK, 0, stream>>>(hist, cursor);
        hsnt_scatter<<<grid, 256, 0, stream>>>(uv, cursor, uvs, inv);
        hsnt_sample_b<<<grid, 256, 0, stream>>>(uvs, tex, tmp);
        hsnt_unperm<<<grid, 256, 0, stream>>>(inv, tmp, out);
    } else if (ws_size >= WS_DIRECT && d_ws != nullptr) {
        __half* tex = (__half*)d_ws;
        hsnt_transpose_h<<<TOT_TEXELS / 256, 256, 0, stream>>>(data, tex);
        hsnt_sample_h<<<grid, 256, 0, stream>>>(uv, tex, out);
    } else {
        hsnt_naive<<<grid, 256, 0, stream>>>(uv, data, out);
    }
}

// Round 6
// 136.420 us; speedup vs baseline: 2.5222x; 2.5222x over previous
//
#include <hip/hip_runtime.h>
#include <hip/hip_fp16.h>

// HierarchicalStaticNeuralTexture — round 6: UV-bucketed gather with
// atomic-free two-level counting sort.
//
//   uv_inputs: [1, 2, 1024, 1024] f32, coords in [-1,1]
//   data:      [1, 16, 2048, 1024] f32  (4 mip levels stacked in Y)
//   out:       [1, 16, 1024, 1024] f32 = sum over 4 levels of bilinear
//              grid_sample (border padding, align_corners=False)
//
// Pipeline:
//   1. transpose_h : atlas -> fp16 texel-major (32 B / texel)
//   2. hist2       : per-1024px-block LDS histogram -> cnt[blk][1024]
//   3. scan_a      : 32 WGs, exclusive prefix of cnt within 32-block chunks
//                    (in place), chunk sums -> wgsum[32][1024]
//   4. scan_b      : 1 WG: bucket bases (LDS scan) + chunk offsets -> wgoff
//   5. scatter2    : LDS ranks + (wgoff+locoff) -> uvs[pos], inv[idx]=pos
//   6. sample_b    : sorted-order sampling (bucket-local L2 reuse) -> fp16 tmp
//   7. unperm      : gather tmp by rank, write channel planes

#define IMG 1024
#define NPIX (IMG * IMG)
#define NCH 16
#define DATA_ROWSTRIDE 1024
#define DATA_CHSTRIDE (2048 * 1024)
#define NBUCK 1024
#define NBLK 1024            // sort blocks, 1024 px each
#define NW 32                // chunks of 32 blocks

// Compact texel-major layout (texel index -> 16 halves)
#define L0_BASE 0
#define L1_BASE 1048576
#define L2_BASE 1310720
#define L3_BASE 1376256
#define TOT_TEXELS 1392640

// Workspace layout (bytes). cnt/wgsum/wgoff alias the head of tmp:
// they are dead before sample_b writes tmp.
#define TEX_BYTES  44564480ull
#define UVS_OFF    44564480ull                    // float2 * NPIX = 8 MB
#define INV_OFF    52953088ull                    // u32 * NPIX   = 4 MB
#define TMP_OFF    57147392ull                    // half*16*NPIX = 32 MB
#define CNT_OFF    TMP_OFF                        // u32[1024][1024] = 4 MB
#define WGS_OFF    (CNT_OFF + 4194304ull)         // u32[32][1024] = 128 KB
#define WGO_OFF    (WGS_OFF + 131072ull)          // u32[32][1024] = 128 KB
#define WS_FULL    90701824ull                    // proven available (r5)
#define WS_DIRECT  TEX_BYTES

// ---------------- transpose+quantize -----------------------------------------
__global__ __launch_bounds__(256) void hsnt_transpose_h(
    const float* __restrict__ data, __half* __restrict__ tex)
{
    int b = blockIdx.x;
    int base, offY, logW;
    if (b < 4096)      { base = L0_BASE; offY = 0;    logW = 10; }
    else if (b < 5120) { base = L1_BASE; offY = 1024; logW = 9;  b -= 4096; }
    else if (b < 5376) { base = L2_BASE; offY = 1536; logW = 8;  b -= 5120; }
    else               { base = L3_BASE; offY = 1792; logW = 7;  b -= 5376; }

    const int t = b * 256 + threadIdx.x;
    const int y = t >> logW;
    const int x = t & ((1 << logW) - 1);

    const float* src = data + (size_t)(offY + y) * DATA_ROWSTRIDE + x;
    __half h[NCH];
#pragma unroll
    for (int c = 0; c < NCH; ++c)
        h[c] = __float2half(src[(size_t)c * DATA_CHSTRIDE]);

    uint4* dst = (uint4*)(tex + ((size_t)(base + t) << 4));
    dst[0] = *(const uint4*)&h[0];
    dst[1] = *(const uint4*)&h[8];
}

// ---------------- bucket key: 32x32 tiles of the L0 texel grid ---------------
__device__ __forceinline__ int bucket_of(const float gx, const float gy)
{
    const float x = fminf(fmaxf(fmaf(gx + 1.0f, 512.0f, -0.5f), 0.0f), 1023.0f);
    const float y = fminf(fmaxf(fmaf(gy + 1.0f, 512.0f, -0.5f), 0.0f), 1023.0f);
    return (((int)y) >> 5) * 32 + (((int)x) >> 5);
}

// ---------------- per-block histogram ----------------------------------------
__global__ __launch_bounds__(256) void hsnt_hist2(
    const float* __restrict__ uv, unsigned* __restrict__ cnt)
{
    __shared__ unsigned lh[NBUCK];
    const int blk = blockIdx.x;
    for (int i = threadIdx.x; i < NBUCK; i += 256) lh[i] = 0u;
    __syncthreads();

    const int base = blk * 1024;
#pragma unroll
    for (int k = 0; k < 4; ++k) {
        const int idx = base + k * 256 + threadIdx.x;
        atomicAdd(&lh[bucket_of(uv[idx], uv[NPIX + idx])], 1u);
    }
    __syncthreads();
    unsigned* row = cnt + (size_t)blk * NBUCK;
    for (int i = threadIdx.x; i < NBUCK; i += 256) row[i] = lh[i];
}

// ---------------- chunk-level exclusive scan (in place) ----------------------
__global__ __launch_bounds__(1024) void hsnt_scan_a(
    unsigned* __restrict__ cnt, unsigned* __restrict__ wgsum)
{
    const int w = blockIdx.x;         // chunk id, 32 blocks each
    const int b = threadIdx.x;        // bucket
    unsigned sum = 0u;
#pragma unroll 4
    for (int r = 0; r < 32; ++r) {
        unsigned* p = cnt + (size_t)(w * 32 + r) * NBUCK + b;
        const unsigned v = *p;
        *p = sum;                     // exclusive within chunk
        sum += v;
    }
    wgsum[w * NBUCK + b] = sum;
}

// ---------------- bucket bases + chunk offsets -------------------------------
__global__ __launch_bounds__(1024) void hsnt_scan_b(
    unsigned* __restrict__ wgsum, unsigned* __restrict__ wgoff)
{
    __shared__ unsigned s[NBUCK];
    const int b = threadIdx.x;

    unsigned tot = 0u;
#pragma unroll 4
    for (int w = 0; w < NW; ++w) tot += wgsum[w * NBUCK + b];

    // exclusive scan of totals over buckets (Hillis-Steele)
    s[b] = tot;
    __syncthreads();
    unsigned acc = tot;
    for (int off = 1; off < NBUCK; off <<= 1) {
        const unsigned add = (b >= off) ? s[b - off] : 0u;
        __syncthreads();
        acc += add;
        s[b] = acc;
        __syncthreads();
    }
    unsigned run = acc - tot;         // exclusive bucket base

#pragma unroll 4
    for (int w = 0; w < NW; ++w) {
        const unsigned v = wgsum[w * NBUCK + b];
        wgoff[w * NBUCK + b] = run;
        run += v;
    }
}

// ---------------- scatter (LDS ranks, no global atomics) ---------------------
__global__ __launch_bounds__(256) void hsnt_scatter2(
    const float* __restrict__ uv,
    const unsigned* __restrict__ cnt,     // now chunk-local exclusive offsets
    const unsigned* __restrict__ wgoff,
    float2* __restrict__ uvs, unsigned* __restrict__ inv)
{
    __shared__ unsigned lh[NBUCK];
    __shared__ unsigned lbase[NBUCK];
    const int blk = blockIdx.x;

    for (int i = threadIdx.x; i < NBUCK; i += 256) lh[i] = 0u;
    __syncthreads();

    const int base = blk * 1024;
    float gx[4], gy[4];
    int bk[4];
    unsigned rk[4];
#pragma unroll
    for (int k = 0; k < 4; ++k) {
        const int idx = base + k * 256 + threadIdx.x;
        gx[k] = uv[idx];
        gy[k] = uv[NPIX + idx];
        bk[k] = bucket_of(gx[k], gy[k]);
        rk[k] = atomicAdd(&lh[bk[k]], 1u);     // LDS rank
    }

    const unsigned* crow = cnt + (size_t)blk * NBUCK;
    const unsigned* wrow = wgoff + (size_t)(blk >> 5) * NBUCK;
    for (int i = threadIdx.x; i < NBUCK; i += 256)
        lbase[i] = crow[i] + wrow[i];
    __syncthreads();

#pragma unroll
    for (int k = 0; k < 4; ++k) {
        const int idx = base + k * 256 + threadIdx.x;
        const unsigned pos = lbase[bk[k]] + rk[k];
        uvs[pos] = make_float2(gx[k], gy[k]);
        inv[idx] = pos;
    }
}

// ---------------- bucketed sampling ------------------------------------------
__device__ __forceinline__ void accum_texel(
    float* __restrict__ acc, const __half* __restrict__ tp, const float w)
{
    union U { uint4 u; __half2 h[4]; } a, b;
    a.u = *(const uint4*)tp;
    b.u = *(const uint4*)(tp + 8);
#pragma unroll
    for (int i = 0; i < 4; ++i) {
        const float2 f = __half22float2(a.h[i]);
        acc[2 * i]     = fmaf(f.x, w, acc[2 * i]);
        acc[2 * i + 1] = fmaf(f.y, w, acc[2 * i + 1]);
        const float2 g = __half22float2(b.h[i]);
        acc[8 + 2 * i]     = fmaf(g.x, w, acc[8 + 2 * i]);
        acc[8 + 2 * i + 1] = fmaf(g.y, w, acc[8 + 2 * i + 1]);
    }
}

__global__ __launch_bounds__(256) void hsnt_sample_b(
    const float2* __restrict__ uvs,
    const __half* __restrict__ tex,
    __half* __restrict__ tmp)
{
    // XCD-chunked swizzle: each XCD walks a contiguous range of sorted order
    const int bid = blockIdx.x;
    const int swz = (bid & 7) * (4096 / 8) + (bid >> 3);
    const int s = swz * 256 + threadIdx.x;

    const float2 g = uvs[s];
    const float gx = g.x;
    const float gy = g.y;

    float acc[NCH];
#pragma unroll
    for (int c = 0; c < NCH; ++c) acc[c] = 0.0f;

    const int BASE[4] = { L0_BASE, L1_BASE, L2_BASE, L3_BASE };

#pragma unroll
    for (int l = 0; l < 4; ++l) {
        const int   W  = 1024 >> l;
        const float Wf = (float)W;

        float x = fminf(fmaxf(fmaf(gx + 1.0f, Wf * 0.5f, -0.5f), 0.0f), Wf - 1.0f);
        float y = fminf(fmaxf(fmaf(gy + 1.0f, Wf * 0.5f, -0.5f), 0.0f), Wf - 1.0f);

        const float x0f = floorf(x);
        const float y0f = floorf(y);
        const float wx = x - x0f;
        const float wy = y - y0f;
        const int x0 = (int)x0f;
        const int y0 = (int)y0f;
        const int x1 = min(x0 + 1, W - 1);
        const int y1 = min(y0 + 1, W - 1);

        const float w11 = wx * wy;
        const float w10 = wy - w11;
        const float w01 = wx - w11;
        const float w00 = 1.0f - wx - wy + w11;

        const int r0 = BASE[l] + y0 * W;
        const int r1 = BASE[l] + y1 * W;

        accum_texel(acc, tex + ((size_t)(r0 + x0) << 4), w00);
        accum_texel(acc, tex + ((size_t)(r0 + x1) << 4), w01);
        accum_texel(acc, tex + ((size_t)(r1 + x0) << 4), w10);
        accum_texel(acc, tex + ((size_t)(r1 + x1) << 4), w11);
    }

    __half h[NCH];
#pragma unroll
    for (int c = 0; c < NCH; ++c) h[c] = __float2half(acc[c]);

    uint4* dst = (uint4*)(tmp + ((size_t)s << 4));
    dst[0] = *(const uint4*)&h[0];
    dst[1] = *(const uint4*)&h[8];
}

// ---------------- unpermute --------------------------------------------------
__global__ __launch_bounds__(256) void hsnt_unperm(
    const unsigned* __restrict__ inv,
    const __half* __restrict__ tmp,
    float* __restrict__ out)
{
    const int idx = blockIdx.x * 256 + threadIdx.x;
    const unsigned r = inv[idx];

    const uint4* p = (const uint4*)(tmp + ((size_t)r << 4));
    union U { uint4 u; __half2 h[4]; } a, b;
    a.u = p[0];
    b.u = p[1];

#pragma unroll
    for (int i = 0; i < 4; ++i) {
        const float2 f = __half22float2(a.h[i]);
        out[(size_t)(2 * i)     * NPIX + idx] = f.x;
        out[(size_t)(2 * i + 1) * NPIX + idx] = f.y;
        const float2 q = __half22float2(b.h[i]);
        out[(size_t)(8 + 2 * i)     * NPIX + idx] = q.x;
        out[(size_t)(8 + 2 * i + 1) * NPIX + idx] = q.y;
    }
}

// ---------------- direct fp16 path (fallback) --------------------------------
__global__ __launch_bounds__(256) void hsnt_sample_h(
    const float* __restrict__ uv,
    const __half* __restrict__ tex,
    float* __restrict__ out)
{
    const int idx = blockIdx.x * blockDim.x + threadIdx.x;
    if (idx >= NPIX) return;

    const float gx = uv[idx];
    const float gy = uv[NPIX + idx];

    float acc[NCH];
#pragma unroll
    for (int c = 0; c < NCH; ++c) acc[c] = 0.0f;

    const int BASE[4] = { L0_BASE, L1_BASE, L2_BASE, L3_BASE };

#pragma unroll
    for (int l = 0; l < 4; ++l) {
        const int   W  = 1024 >> l;
        const float Wf = (float)W;
        float x = fminf(fmaxf(fmaf(gx + 1.0f, Wf * 0.5f, -0.5f), 0.0f), Wf - 1.0f);
        float y = fminf(fmaxf(fmaf(gy + 1.0f, Wf * 0.5f, -0.5f), 0.0f), Wf - 1.0f);
        const float x0f = floorf(x);
        const float y0f = floorf(y);
        const float wx = x - x0f;
        const float wy = y - y0f;
        const int x0 = (int)x0f;
        const int y0 = (int)y0f;
        const int x1 = min(x0 + 1, W - 1);
        const int y1 = min(y0 + 1, W - 1);
        const float w11 = wx * wy;
        const float w10 = wy - w11;
        const float w01 = wx - w11;
        const float w00 = 1.0f - wx - wy + w11;
        const int r0 = BASE[l] + y0 * W;
        const int r1 = BASE[l] + y1 * W;
        accum_texel(acc, tex + ((size_t)(r0 + x0) << 4), w00);
        accum_texel(acc, tex + ((size_t)(r0 + x1) << 4), w01);
        accum_texel(acc, tex + ((size_t)(r1 + x0) << 4), w10);
        accum_texel(acc, tex + ((size_t)(r1 + x1) << 4), w11);
    }

#pragma unroll
    for (int c = 0; c < NCH; ++c)
        out[(size_t)c * NPIX + idx] = acc[c];
}

// ---------------- naive fallback ---------------------------------------------
__global__ __launch_bounds__(256) void hsnt_naive(
    const float* __restrict__ uv,
    const float* __restrict__ data,
    float* __restrict__ out)
{
    const int idx = blockIdx.x * blockDim.x + threadIdx.x;
    if (idx >= NPIX) return;

    const float gx = uv[idx];
    const float gy = uv[NPIX + idx];

    float acc[NCH];
#pragma unroll
    for (int c = 0; c < NCH; ++c) acc[c] = 0.0f;

    int offY = 0;
    int W = 1024;
#pragma unroll
    for (int l = 0; l < 4; ++l) {
        const float Wf = (float)W;
        float x = fminf(fmaxf(fmaf(gx + 1.0f, Wf * 0.5f, -0.5f), 0.0f), Wf - 1.0f);
        float y = fminf(fmaxf(fmaf(gy + 1.0f, Wf * 0.5f, -0.5f), 0.0f), Wf - 1.0f);
        const float x0f = floorf(x);
        const float y0f = floorf(y);
        const float wx = x - x0f;
        const float wy = y - y0f;
        const int x0 = (int)x0f;
        const int y0 = (int)y0f;
        const int x1 = min(x0 + 1, W - 1);
        const int y1 = min(y0 + 1, W - 1);
        const float w11 = wx * wy;
        const float w10 = wy - w11;
        const float w01 = wx - w11;
        const float w00 = 1.0f - wx - wy + w11;
        const int r0 = offY + y0;
        const int r1 = offY + y1;
        const float* p00 = data + (size_t)r0 * DATA_ROWSTRIDE + x0;
        const float* p01 = data + (size_t)r0 * DATA_ROWSTRIDE + x1;
        const float* p10 = data + (size_t)r1 * DATA_ROWSTRIDE + x0;
        const float* p11 = data + (size_t)r1 * DATA_ROWSTRIDE + x1;
#pragma unroll
        for (int c = 0; c < NCH; ++c) {
            const size_t co = (size_t)c * DATA_CHSTRIDE;
            acc[c] = fmaf(p00[co], w00,
                     fmaf(p01[co], w01,
                     fmaf(p10[co], w10,
                     fmaf(p11[co], w11, acc[c]))));
        }
        offY += W;
        W >>= 1;
    }
#pragma unroll
    for (int c = 0; c < NCH; ++c)
        out[(size_t)c * NPIX + idx] = acc[c];
}

extern "C" void kernel_launch(void* const* d_in, const int* in_sizes, int n_in,
                              void* d_out, int out_size, void* d_ws, size_t ws_size,
                              hipStream_t stream) {
    const float* uv   = (const float*)d_in[0];   // [1,2,1024,1024]
    const float* data = (const float*)d_in[1];   // [1,16,2048,1024]
    float* out = (float*)d_out;                  // [1,16,1024,1024]

    const int grid = NPIX / 256;                 // 4096

    if (ws_size >= WS_FULL && d_ws != nullptr) {
        char* ws = (char*)d_ws;
        __half*   tex   = (__half*)ws;
        float2*   uvs   = (float2*)(ws + UVS_OFF);
        unsigned* inv   = (unsigned*)(ws + INV_OFF);
        __half*   tmp   = (__half*)(ws + TMP_OFF);
        unsigned* cnt   = (unsigned*)(ws + CNT_OFF);   // aliases tmp head
        unsigned* wgsum = (unsigned*)(ws + WGS_OFF);
        unsigned* wgoff = (unsigned*)(ws + WGO_OFF);

        hsnt_transpose_h<<<TOT_TEXELS / 256, 256, 0, stream>>>(data, tex);
        hsnt_hist2<<<NBLK, 256, 0, stream>>>(uv, cnt);
        hsnt_scan_a<<<NW, 1024, 0, stream>>>(cnt, wgsum);
        hsnt_scan_b<<<1, 1024, 0, stream>>>(wgsum, wgoff);
        hsnt_scatter2<<<NBLK, 256, 0, stream>>>(uv, cnt, wgoff, uvs, inv);
        hsnt_sample_b<<<grid, 256, 0, stream>>>(uvs, tex, tmp);
        hsnt_unperm<<<grid, 256, 0, stream>>>(inv, tmp, out);
    } else if (ws_size >= WS_DIRECT && d_ws != nullptr) {
        __half* tex = (__half*)d_ws;
        hsnt_transpose_h<<<TOT_TEXELS / 256, 256, 0, stream>>>(data, tex);
        hsnt_sample_h<<<grid, 256, 0, stream>>>(uv, tex, out);
    } else {
        hsnt_naive<<<grid, 256, 0, stream>>>(uv, data, out);
    }
}